// Round 7
// baseline (54.239 us; speedup 1.0000x reference)
//
#include <hip/hip_runtime.h>

// Focal loss, mean-reduced. inputs: [B,T,2] f32; targets: [B,T] int32 (0/1).
// B=T=4096. out: 1 float (mean over B*T*2 elements).
//
// R7: single kernel. R1-proven main loop (all pipeline attempts R3/R5/R6
// were flattened by the compiler at identical perf). Tail = per-block LDS
// reduce + ONE f32 atomicAdd to out[0] (pre-scaled). out zeroed per call
// via capture-legal hipMemsetAsync. No partials, no fences, no 2nd launch.

constexpr unsigned NPOS    = 4096u * 4096u;              // B*T positions
constexpr int      BLOCKS  = 2048;                       // 8 blocks/CU exactly
constexpr int      THREADS = 256;
constexpr unsigned NQUAD   = NPOS / 4;                   // 4 positions / iter
constexpr unsigned STRIDE  = (unsigned)BLOCKS * THREADS; // 524288
constexpr int      ITERS   = (int)(NQUAD / STRIDE);      // exactly 8

// g(z) = (1 - sigma(z))^2 * (-log sigma(z)) ; sigma(z) = 1/(1+exp(-z))
// element (x, ts): ts==1 -> ALPHA * g(x) ; ts==0 -> (1-ALPHA) * g(-x)
__device__ __forceinline__ float g_of(float z) {
    float e   = __expf(-z);
    float u   = 1.f + e;
    float pt  = __builtin_amdgcn_rcpf(u);   // sigma(z)
    float bce = __logf(u);                  // -log sigma(z) = log1p(e^-z)
    float om  = e * pt;                     // 1 - sigma(z), no cancellation
    return om * om * bce;
}

__global__ __launch_bounds__(THREADS) void focal_onepass(
    const float4* __restrict__ in,     // float4 = 2 positions (x=c0,y=c1,z=c0,w=c1)
    const int4*   __restrict__ tgt,    // int4   = 4 positions
    float*        __restrict__ out)    // single accumulator, zeroed per call
{
    const unsigned tid = blockIdx.x * (unsigned)THREADS + threadIdx.x;

    float acc_t = 0.f;   // true-class terms  (weight 0.25)
    float acc_f = 0.f;   // false-class terms (weight 0.75)

#pragma unroll
    for (int i = 0; i < ITERS; ++i) {
        unsigned q  = tid + (unsigned)i * STRIDE;
        float4   v0 = in[2u * q];
        float4   v1 = in[2u * q + 1u];
        int4     t4 = tgt[q];

        float x0[4] = {v0.x, v0.z, v1.x, v1.z};   // class-0 logits
        float x1[4] = {v0.y, v0.w, v1.y, v1.w};   // class-1 logits
        int   tt[4] = {t4.x, t4.y, t4.z, t4.w};

#pragma unroll
        for (int p = 0; p < 4; ++p) {
            bool  one = tt[p] != 0;
            float xt  = one ? x1[p] : x0[p];      // true-class logit
            float xf  = one ? x0[p] : x1[p];      // false-class logit
            acc_t += g_of(xt);
            acc_f += g_of(-xf);
        }
    }

    float acc = 0.25f * acc_t + 0.75f * acc_f;

    // wave (64-lane) reduction
#pragma unroll
    for (int off = 32; off > 0; off >>= 1)
        acc += __shfl_down(acc, off, 64);

    __shared__ float sm[THREADS / 64];
    const int lane = threadIdx.x & 63;
    const int wid  = threadIdx.x >> 6;
    if (lane == 0) sm[wid] = acc;
    __syncthreads();
    if (threadIdx.x == 0) {
        float s = 0.f;
#pragma unroll
        for (int w = 0; w < THREADS / 64; ++w) s += sm[w];
        // one device-scope f32 atomic per block; pre-scaled so out = mean
        atomicAdd(out, s * (1.0f / (2.0f * (float)NPOS)));
    }
}

extern "C" void kernel_launch(void* const* d_in, const int* in_sizes, int n_in,
                              void* d_out, int out_size, void* d_ws, size_t ws_size,
                              hipStream_t stream) {
    const float4* in  = (const float4*)d_in[0];
    const int4*   tgt = (const int4*)d_in[1];
    float* out        = (float*)d_out;

    hipMemsetAsync(out, 0, sizeof(float), stream);   // capture-legal node
    focal_onepass<<<BLOCKS, THREADS, 0, stream>>>(in, tgt, out);
}

// Round 8
// 49.299 us; speedup vs baseline: 1.1002x; 1.1002x over previous
//
#include <hip/hip_runtime.h>

// Focal loss, mean-reduced. inputs: [B,T,2] f32; targets: [B,T] int32 (0/1).
// B=T=4096. out: 1 float (mean over B*T*2 elements).
//
// R8: single kernel, NO memset node (R4/R7 decomposition: in-graph tiny
// hipMemsetAsync costs ~15.5us; tail protocols were ~free). Arrival counter
// is a __device__ module global (zeroed at load); election via
// (old & (BLOCKS-1)) == BLOCKS-1, so no per-call init is needed and every
// call does identical work. Tail = R4's correctness-proven relaxed
// agent-scope protocol (no L2-writeback fences).

constexpr unsigned NPOS    = 4096u * 4096u;              // B*T positions
constexpr int      BLOCKS  = 2048;                       // power of two
constexpr int      THREADS = 256;
constexpr unsigned NQUAD   = NPOS / 4;                   // 4 positions / iter
constexpr unsigned STRIDE  = (unsigned)BLOCKS * THREADS; // 524288
constexpr int      ITERS   = (int)(NQUAD / STRIDE);      // exactly 8

__device__ unsigned g_arrive = 0;   // monotonic across calls; mod-2048 election

// g(z) = (1 - sigma(z))^2 * (-log sigma(z)) ; sigma(z) = 1/(1+exp(-z))
// element (x, ts): ts==1 -> ALPHA * g(x) ; ts==0 -> (1-ALPHA) * g(-x)
__device__ __forceinline__ float g_of(float z) {
    float e   = __expf(-z);
    float u   = 1.f + e;
    float pt  = __builtin_amdgcn_rcpf(u);   // sigma(z)
    float bce = __logf(u);                  // -log sigma(z) = log1p(e^-z)
    float om  = e * pt;                     // 1 - sigma(z), no cancellation
    return om * om * bce;
}

__global__ __launch_bounds__(THREADS) void focal_fused(
    const float4* __restrict__ in,     // float4 = 2 positions (x=c0,y=c1,z=c0,w=c1)
    const int4*   __restrict__ tgt,    // int4   = 4 positions
    float*        __restrict__ partial,   // [BLOCKS] in d_ws
    float*        __restrict__ out)
{
    const unsigned tid = blockIdx.x * (unsigned)THREADS + threadIdx.x;

    float acc_t = 0.f;   // true-class terms  (weight 0.25)
    float acc_f = 0.f;   // false-class terms (weight 0.75)

#pragma unroll
    for (int i = 0; i < ITERS; ++i) {
        unsigned q  = tid + (unsigned)i * STRIDE;
        float4   v0 = in[2u * q];
        float4   v1 = in[2u * q + 1u];
        int4     t4 = tgt[q];

        float x0[4] = {v0.x, v0.z, v1.x, v1.z};   // class-0 logits
        float x1[4] = {v0.y, v0.w, v1.y, v1.w};   // class-1 logits
        int   tt[4] = {t4.x, t4.y, t4.z, t4.w};

#pragma unroll
        for (int p = 0; p < 4; ++p) {
            bool  one = tt[p] != 0;
            float xt  = one ? x1[p] : x0[p];      // true-class logit
            float xf  = one ? x0[p] : x1[p];      // false-class logit
            acc_t += g_of(xt);
            acc_f += g_of(-xf);
        }
    }

    float acc = 0.25f * acc_t + 0.75f * acc_f;

    // wave (64-lane) reduction
#pragma unroll
    for (int off = 32; off > 0; off >>= 1)
        acc += __shfl_down(acc, off, 64);

    __shared__ float sm[THREADS / 64];
    __shared__ bool  amLast;
    const int lane = threadIdx.x & 63;
    const int wid  = threadIdx.x >> 6;
    if (lane == 0) sm[wid] = acc;
    __syncthreads();

    if (threadIdx.x == 0) {
        float s = 0.f;
#pragma unroll
        for (int w = 0; w < THREADS / 64; ++w) s += sm[w];
        // agent-scope write-through store: lands at the device coherence point
        __hip_atomic_store(&partial[blockIdx.x], s,
                           __ATOMIC_RELAXED, __HIP_MEMORY_SCOPE_AGENT);
        // drain store ack before arrival -> observers of the count see our partial
        asm volatile("s_waitcnt vmcnt(0)" ::: "memory");
        unsigned old = __hip_atomic_fetch_add(&g_arrive, 1u,
                           __ATOMIC_RELAXED, __HIP_MEMORY_SCOPE_AGENT);
        amLast = ((old & (unsigned)(BLOCKS - 1)) == (unsigned)(BLOCKS - 1));
    }
    __syncthreads();

    if (amLast) {
        float s = 0.f;
        for (int i = threadIdx.x; i < BLOCKS; i += THREADS)
            s += __hip_atomic_load(&partial[i],
                     __ATOMIC_RELAXED, __HIP_MEMORY_SCOPE_AGENT);  // fixed order
#pragma unroll
        for (int off = 32; off > 0; off >>= 1)
            s += __shfl_down(s, off, 64);
        if (lane == 0) sm[wid] = s;
        __syncthreads();
        if (threadIdx.x == 0) {
            float tot = sm[0] + sm[1] + sm[2] + sm[3];
            out[0] = tot * (1.0f / (2.0f * (float)NPOS));
        }
    }
}

extern "C" void kernel_launch(void* const* d_in, const int* in_sizes, int n_in,
                              void* d_out, int out_size, void* d_ws, size_t ws_size,
                              hipStream_t stream) {
    const float4* in  = (const float4*)d_in[0];
    const int4*   tgt = (const int4*)d_in[1];
    float* partial    = (float*)d_ws;
    float* out        = (float*)d_out;

    focal_fused<<<BLOCKS, THREADS, 0, stream>>>(in, tgt, partial, out);
}

// Round 9
// 39.069 us; speedup vs baseline: 1.3883x; 1.2619x over previous
//
#include <hip/hip_runtime.h>

// Focal loss, mean-reduced. inputs: [B,T,2] f32; targets: [B,T] int32 (0/1).
// B=T=4096. out: 1 float (mean over B*T*2 elements).
//
// R9: two kernels (all fusion variants cost +10..15us — exhausted).
// R1-proven main loop; grid reshaped 2048x8iter -> 4096x4iter to smooth
// dispatch ramp/drain (Occupancy was 60-67% with exactly-8 blocks/CU).

constexpr unsigned NPOS    = 4096u * 4096u;              // B*T positions
constexpr int      BLOCKS  = 4096;                       // ~16 blocks/CU
constexpr int      THREADS = 256;
constexpr unsigned NQUAD   = NPOS / 4;                   // 4 positions / iter
constexpr unsigned STRIDE  = (unsigned)BLOCKS * THREADS; // 1048576
constexpr int      ITERS   = (int)(NQUAD / STRIDE);      // exactly 4

// g(z) = (1 - sigma(z))^2 * (-log sigma(z)) ; sigma(z) = 1/(1+exp(-z))
// element (x, ts): ts==1 -> ALPHA * g(x) ; ts==0 -> (1-ALPHA) * g(-x)
__device__ __forceinline__ float g_of(float z) {
    float e   = __expf(-z);
    float u   = 1.f + e;
    float pt  = __builtin_amdgcn_rcpf(u);   // sigma(z)
    float bce = __logf(u);                  // -log sigma(z) = log1p(e^-z)
    float om  = e * pt;                     // 1 - sigma(z), no cancellation
    return om * om * bce;
}

__global__ __launch_bounds__(THREADS) void focal_partial(
    const float4* __restrict__ in,     // float4 = 2 positions (x=c0,y=c1,z=c0,w=c1)
    const int4*   __restrict__ tgt,    // int4   = 4 positions
    float*        __restrict__ partial)
{
    const unsigned tid = blockIdx.x * (unsigned)THREADS + threadIdx.x;

    float acc_t = 0.f;   // true-class terms  (weight 0.25)
    float acc_f = 0.f;   // false-class terms (weight 0.75)

#pragma unroll
    for (int i = 0; i < ITERS; ++i) {
        unsigned q  = tid + (unsigned)i * STRIDE;
        float4   v0 = in[2u * q];
        float4   v1 = in[2u * q + 1u];
        int4     t4 = tgt[q];

        float x0[4] = {v0.x, v0.z, v1.x, v1.z};   // class-0 logits
        float x1[4] = {v0.y, v0.w, v1.y, v1.w};   // class-1 logits
        int   tt[4] = {t4.x, t4.y, t4.z, t4.w};

#pragma unroll
        for (int p = 0; p < 4; ++p) {
            bool  one = tt[p] != 0;
            float xt  = one ? x1[p] : x0[p];      // true-class logit
            float xf  = one ? x0[p] : x1[p];      // false-class logit
            acc_t += g_of(xt);
            acc_f += g_of(-xf);
        }
    }

    float acc = 0.25f * acc_t + 0.75f * acc_f;

    // wave (64-lane) reduction
#pragma unroll
    for (int off = 32; off > 0; off >>= 1)
        acc += __shfl_down(acc, off, 64);

    __shared__ float sm[THREADS / 64];
    const int lane = threadIdx.x & 63;
    const int wid  = threadIdx.x >> 6;
    if (lane == 0) sm[wid] = acc;
    __syncthreads();
    if (threadIdx.x == 0) {
        float s = 0.f;
#pragma unroll
        for (int w = 0; w < THREADS / 64; ++w) s += sm[w];
        partial[blockIdx.x] = s;
    }
}

__global__ __launch_bounds__(256) void focal_final(
    const float4* __restrict__ partial4,   // 4096 floats = 1024 float4
    float*        __restrict__ out)
{
    float acc = 0.f;
#pragma unroll
    for (int r = 0; r < 4; ++r) {
        int i = r * 256 + threadIdx.x;
        if (i < BLOCKS / 4) {
            float4 p = partial4[i];
            acc += (p.x + p.y) + (p.z + p.w);
        }
    }
#pragma unroll
    for (int off = 32; off > 0; off >>= 1)
        acc += __shfl_down(acc, off, 64);

    __shared__ float sm[4];
    const int lane = threadIdx.x & 63;
    const int wid  = threadIdx.x >> 6;
    if (lane == 0) sm[wid] = acc;
    __syncthreads();
    if (threadIdx.x == 0) {
        float s = sm[0] + sm[1] + sm[2] + sm[3];
        out[0] = s * (1.0f / (2.0f * (float)NPOS));  // mean over B*T*2 elements
    }
}

extern "C" void kernel_launch(void* const* d_in, const int* in_sizes, int n_in,
                              void* d_out, int out_size, void* d_ws, size_t ws_size,
                              hipStream_t stream) {
    const float4* in  = (const float4*)d_in[0];
    const int4*   tgt = (const int4*)d_in[1];
    float* partial    = (float*)d_ws;
    float* out        = (float*)d_out;

    focal_partial<<<BLOCKS, THREADS, 0, stream>>>(in, tgt, partial);
    focal_final<<<1, 256, 0, stream>>>((const float4*)partial, out);
}